// Round 4
// baseline (502.712 us; speedup 1.0000x reference)
//
#include <hip/hip_runtime.h>
#include <stdint.h>

// TopKMS (OHEM top-k MSE): per-row MSE over [N, 512] fp32, mean of top-30% rows.
// R10: R9 post-mortem -- hand-rolled 1-deep pipeline + sched_barrier collapsed
// MLP (VGPR=32 -> one buffer's worth of landing regs) AND cut TLP 4x: 307 us,
// 0.87 TB/s. The atomics were fine (WRITE_SIZE=4KB). Cross-round A/B table:
//   R6  grid-stride 2rows NT loads 8192 waves  -> <76 us (best ever)
//   R7  4 rows plain      -> 101 us ; R8 one-shot plain -> 93.5 us ; R9 -> 307.
// Conclusion: revert phase A to EXACTLY the R6 loop (grid-stride, 2 rows/iter,
// 8 straight-line NT loads) and keep only the validated R9 win: histogram
// fused via lane-0 fire-and-forget global atomics (rowmse buffer + hist
// kernel + 1 MB of traffic deleted). 32 KB memset zeroes the hist; 32 KB
// single-block scan finishes.

#define D_FEAT 512
#define NBINS 4096          // 256 bins/octave over [2^-8, 2^8)
#define HIST_SHIFT 15       // 8 mantissa bits
#define HIST_BASE (119 << 8)
#define MAIN_BLOCKS 2048
#define MAIN_THREADS 256
#define SEL_THREADS 1024

typedef float f32x4 __attribute__((ext_vector_type(4)));

// ---- Phase A (fused): R6 loop structure + direct histogram atomics ---------
__global__ __launch_bounds__(MAIN_THREADS) void fused_mse_hist_kernel(
    const float* __restrict__ input,
    const float* __restrict__ target,
    int n_rows,
    int* __restrict__ g_cnt,
    float* __restrict__ g_sum)
{
    const int lane   = threadIdx.x & 63;
    const int wave   = (blockIdx.x * MAIN_THREADS + threadIdx.x) >> 6;
    const int nwaves = (MAIN_BLOCKS * MAIN_THREADS) >> 6;   // 8192
    const float inv_d = 1.0f / (float)D_FEAT;

    for (int row = wave * 2; row < n_rows; row += 2 * nwaves) {
        const int row1 = row + 1;
        const bool has1 = (row1 < n_rows);

        const f32x4* __restrict__ a0 = (const f32x4*)(input  + (size_t)row * D_FEAT);
        const f32x4* __restrict__ b0 = (const f32x4*)(target + (size_t)row * D_FEAT);
        const f32x4* __restrict__ a1 = (const f32x4*)(input  + (size_t)(has1 ? row1 : row) * D_FEAT);
        const f32x4* __restrict__ b1 = (const f32x4*)(target + (size_t)(has1 ? row1 : row) * D_FEAT);

        f32x4 A00 = __builtin_nontemporal_load(&a0[lane]);
        f32x4 A01 = __builtin_nontemporal_load(&a0[lane + 64]);
        f32x4 B00 = __builtin_nontemporal_load(&b0[lane]);
        f32x4 B01 = __builtin_nontemporal_load(&b0[lane + 64]);
        f32x4 A10 = __builtin_nontemporal_load(&a1[lane]);
        f32x4 A11 = __builtin_nontemporal_load(&a1[lane + 64]);
        f32x4 B10 = __builtin_nontemporal_load(&b1[lane]);
        f32x4 B11 = __builtin_nontemporal_load(&b1[lane + 64]);

        f32x4 d0 = A00 - B00;
        f32x4 d1 = A01 - B01;
        f32x4 d2 = A10 - B10;
        f32x4 d3 = A11 - B11;

        float acc0 = d0.x * d0.x + d0.y * d0.y + d0.z * d0.z + d0.w * d0.w
                   + d1.x * d1.x + d1.y * d1.y + d1.z * d1.z + d1.w * d1.w;
        float acc1 = d2.x * d2.x + d2.y * d2.y + d2.z * d2.z + d2.w * d2.w
                   + d3.x * d3.x + d3.y * d3.y + d3.z * d3.z + d3.w * d3.w;

        #pragma unroll
        for (int off = 32; off > 0; off >>= 1) {
            acc0 += __shfl_xor(acc0, off, 64);
            acc1 += __shfl_xor(acc1, off, 64);
        }

        if (lane == 0) {
            {
                float v = acc0 * inv_d;
                uint32_t bits = __float_as_uint(v);
                int bin = (int)(bits >> HIST_SHIFT) - HIST_BASE;
                bin = bin < 0 ? 0 : (bin > NBINS - 1 ? NBINS - 1 : bin);
                atomicAdd(&g_cnt[bin], 1);      // fire-and-forget, no readback
                atomicAdd(&g_sum[bin], v);
            }
            if (has1) {
                float v = acc1 * inv_d;
                uint32_t bits = __float_as_uint(v);
                int bin = (int)(bits >> HIST_SHIFT) - HIST_BASE;
                bin = bin < 0 ? 0 : (bin > NBINS - 1 ? NBINS - 1 : bin);
                atomicAdd(&g_cnt[bin], 1);
                atomicAdd(&g_sum[bin], v);
            }
        }
    }
}

// --------- Phase B: single-block scan of the 32 KB histogram ----------------
__global__ __launch_bounds__(SEL_THREADS) void scan_select_kernel(
    const int* __restrict__ g_cnt,
    const float* __restrict__ g_sum,
    int k,
    float* __restrict__ out)
{
    __shared__ int   cnt[NBINS];
    __shared__ float sum[NBINS];
    __shared__ int   cs[SEL_THREADS];
    __shared__ float ss[SEL_THREADS];
    const int t = threadIdx.x;

    for (int i = t; i < NBINS; i += SEL_THREADS) {
        cnt[i] = g_cnt[i];
        sum[i] = g_sum[i];
    }
    __syncthreads();

    // descending chunks: thread t owns bins [start - ch + 1, start]
    const int ch = NBINS / SEL_THREADS;   // 4
    const int start = NBINS - 1 - t * ch;

    int   c_t = 0;
    float s_t = 0.0f;
    #pragma unroll
    for (int j = 0; j < ch; ++j) { c_t += cnt[start - j]; s_t += sum[start - j]; }
    cs[t] = c_t;
    ss[t] = s_t;
    __syncthreads();

    // Hillis-Steele inclusive scan (top -> bottom order)
    for (int off = 1; off < SEL_THREADS; off <<= 1) {
        int cv = 0; float sv = 0.0f;
        if (t >= off) { cv = cs[t - off]; sv = ss[t - off]; }
        __syncthreads();
        cs[t] += cv;
        ss[t] += sv;
        __syncthreads();
    }

    const int   c_incl   = cs[t];
    const int   c_before = c_incl - c_t;
    const float s_before = ss[t] - s_t;

    if (c_before < k && k <= c_incl) {
        int   cum = c_before;
        float s   = s_before;
        float result = 0.0f;
        for (int j = 0; j < ch; ++j) {
            int b = start - j;
            int c = cnt[b];
            if (c == 0) continue;
            if (cum + c >= k) {
                int need = k - cum;
                float avg = sum[b] / (float)c;   // bin mean, tighter than center
                result = (s + (float)need * avg) / (float)k;
                break;
            }
            cum += c;
            s   += sum[b];
        }
        out[0] = result;
    }
}

extern "C" void kernel_launch(void* const* d_in, const int* in_sizes, int n_in,
                              void* d_out, int out_size, void* d_ws, size_t ws_size,
                              hipStream_t stream)
{
    const float* input  = (const float*)d_in[0];
    const float* target = (const float*)d_in[1];
    float* out = (float*)d_out;

    const int total  = in_sizes[0];
    const int n_rows = total / D_FEAT;            // 65536
    int k = (int)(0.3 * (double)n_rows);          // matches int(K_FRAC * n)
    if (k < 1) k = 1;
    if (k > n_rows) k = n_rows;

    // Histogram at the start of the workspace: g_cnt[NBINS] then g_sum[NBINS].
    int*   g_cnt = (int*)d_ws;
    float* g_sum = (float*)((char*)d_ws + (size_t)NBINS * sizeof(int));

    // Zero the 32 KB histogram (stream-ordered, graph-capturable).
    hipMemsetAsync(d_ws, 0, (size_t)NBINS * (sizeof(int) + sizeof(float)), stream);

    fused_mse_hist_kernel<<<MAIN_BLOCKS, MAIN_THREADS, 0, stream>>>(
        input, target, n_rows, g_cnt, g_sum);

    scan_select_kernel<<<1, SEL_THREADS, 0, stream>>>(g_cnt, g_sum, k, out);
}

// Round 5
// 256.467 us; speedup vs baseline: 1.9601x; 1.9601x over previous
//
#include <hip/hip_runtime.h>
#include <stdint.h>

// TopKMS (OHEM top-k MSE): per-row MSE over [N, 512] fp32, mean of top-30% rows.
// R11: R10 completed the decisive A/B -- the EXACT R6 loop (<=76us proven)
// fused with direct histogram atomics ran 294us. Culprit: same-address
// device-scope atomic serialization. Row-MSE concentrates at 2.0+/-0.125 ->
// hottest bin collects ~1600 rows; ~1600 serialized RMWs x ~180ns ~= 290us,
// matching R9 (307) and R10 (294). WRITE_SIZE=4KB proves it's latency
// serialization, not bandwidth.
// Fix: compose the two best MEASURED pieces, change nothing else:
//   Phase A = exact R6 kernel (NT loads, grid-stride, 2 rows/wave, scalar
//             rowmse stores) + R8's free block-0 hist zeroing (no memset).
//   Phase B = R8's 64-block LDS-privatized hist (same-address depth <=64,
//             flush order rotated per block) + 32KB single-block scan.

#define D_FEAT 512
#define NBINS 4096          // 256 bins/octave over [2^-8, 2^8)
#define HIST_SHIFT 15       // 8 mantissa bits
#define HIST_BASE (119 << 8)
#define MAIN_BLOCKS 2048
#define MAIN_THREADS 256
#define HB_BLOCKS 64
#define HB_THREADS 256
#define SEL_THREADS 1024

typedef float f32x4 __attribute__((ext_vector_type(4)));

// ---------------- Phase A: per-row MSE, grid-stride, NT loads ----------------
// Exact R6 structure (best measured phase A). Block 0 additionally zeroes the
// 32KB global histogram (stream-order guarantees visibility to hist_kernel).
__global__ __launch_bounds__(MAIN_THREADS) void mse_rows_kernel(
    const float* __restrict__ input,
    const float* __restrict__ target,
    int n_rows,
    float* __restrict__ rowmse,
    int* __restrict__ g_cnt,
    float* __restrict__ g_sum)
{
    if (blockIdx.x == 0) {
        for (int i = threadIdx.x; i < NBINS; i += MAIN_THREADS) {
            g_cnt[i] = 0;
            g_sum[i] = 0.0f;
        }
    }

    const int lane   = threadIdx.x & 63;
    const int wave   = (blockIdx.x * MAIN_THREADS + threadIdx.x) >> 6;
    const int nwaves = (MAIN_BLOCKS * MAIN_THREADS) >> 6;   // 8192
    const float inv_d = 1.0f / (float)D_FEAT;

    for (int row = wave * 2; row < n_rows; row += 2 * nwaves) {
        const int row1 = row + 1;
        const bool has1 = (row1 < n_rows);

        const f32x4* __restrict__ a0 = (const f32x4*)(input  + (size_t)row * D_FEAT);
        const f32x4* __restrict__ b0 = (const f32x4*)(target + (size_t)row * D_FEAT);
        const f32x4* __restrict__ a1 = (const f32x4*)(input  + (size_t)(has1 ? row1 : row) * D_FEAT);
        const f32x4* __restrict__ b1 = (const f32x4*)(target + (size_t)(has1 ? row1 : row) * D_FEAT);

        f32x4 A00 = __builtin_nontemporal_load(&a0[lane]);
        f32x4 A01 = __builtin_nontemporal_load(&a0[lane + 64]);
        f32x4 B00 = __builtin_nontemporal_load(&b0[lane]);
        f32x4 B01 = __builtin_nontemporal_load(&b0[lane + 64]);
        f32x4 A10 = __builtin_nontemporal_load(&a1[lane]);
        f32x4 A11 = __builtin_nontemporal_load(&a1[lane + 64]);
        f32x4 B10 = __builtin_nontemporal_load(&b1[lane]);
        f32x4 B11 = __builtin_nontemporal_load(&b1[lane + 64]);

        f32x4 d0 = A00 - B00;
        f32x4 d1 = A01 - B01;
        f32x4 d2 = A10 - B10;
        f32x4 d3 = A11 - B11;

        float acc0 = d0.x * d0.x + d0.y * d0.y + d0.z * d0.z + d0.w * d0.w
                   + d1.x * d1.x + d1.y * d1.y + d1.z * d1.z + d1.w * d1.w;
        float acc1 = d2.x * d2.x + d2.y * d2.y + d2.z * d2.z + d2.w * d2.w
                   + d3.x * d3.x + d3.y * d3.y + d3.z * d3.z + d3.w * d3.w;

        #pragma unroll
        for (int off = 32; off > 0; off >>= 1) {
            acc0 += __shfl_xor(acc0, off, 64);
            acc1 += __shfl_xor(acc1, off, 64);
        }

        if (lane == 0) {
            rowmse[row] = acc0 * inv_d;
            if (has1) rowmse[row1] = acc1 * inv_d;
        }
    }
}

// ------- Phase B1: per-block LDS histogram -> global atomic merge -----------
// 64 blocks x 1024 rows: LDS privatization caps same-address global-atomic
// depth at 64. Flush order rotated per block to decorrelate hot-bin bursts.
__global__ __launch_bounds__(HB_THREADS) void hist_kernel(
    const float* __restrict__ rowmse,
    int n_rows,
    int* __restrict__ g_cnt,
    float* __restrict__ g_sum)
{
    __shared__ int   cnt[NBINS];
    __shared__ float sum[NBINS];
    const int t = threadIdx.x;

    for (int i = t; i < NBINS; i += HB_THREADS) { cnt[i] = 0; sum[i] = 0.0f; }
    __syncthreads();

    const int chunk = (n_rows + HB_BLOCKS - 1) / HB_BLOCKS;   // 1024
    const int lo = blockIdx.x * chunk;
    const int hi = min(n_rows, lo + chunk);

    for (int i = lo + t; i < hi; i += HB_THREADS) {
        float v = rowmse[i];
        uint32_t bits = __float_as_uint(v);
        int bin = (int)(bits >> HIST_SHIFT) - HIST_BASE;
        bin = bin < 0 ? 0 : (bin > NBINS - 1 ? NBINS - 1 : bin);
        atomicAdd(&cnt[bin], 1);    // LDS-scope, ~1k rows/block
        atomicAdd(&sum[bin], v);
    }
    __syncthreads();

    // Flush only non-empty bins; rotate stripe order by blockIdx so different
    // blocks hit the hot bin range at different times.
    const int nstripes = NBINS / HB_THREADS;   // 16
    for (int s = 0; s < nstripes; ++s) {
        const int stripe = (s + blockIdx.x) & (nstripes - 1);
        const int i = stripe * HB_THREADS + t;
        int c = cnt[i];
        if (c != 0) {
            atomicAdd(&g_cnt[i], c);
            atomicAdd(&g_sum[i], sum[i]);
        }
    }
}

// --------- Phase B2: single-block scan of the 32 KB histogram ---------------
__global__ __launch_bounds__(SEL_THREADS) void scan_select_kernel(
    const int* __restrict__ g_cnt,
    const float* __restrict__ g_sum,
    int k,
    float* __restrict__ out)
{
    __shared__ int   cnt[NBINS];
    __shared__ float sum[NBINS];
    __shared__ int   cs[SEL_THREADS];
    __shared__ float ss[SEL_THREADS];
    const int t = threadIdx.x;

    for (int i = t; i < NBINS; i += SEL_THREADS) {
        cnt[i] = g_cnt[i];
        sum[i] = g_sum[i];
    }
    __syncthreads();

    // descending chunks: thread t owns bins [start - ch + 1, start]
    const int ch = NBINS / SEL_THREADS;   // 4
    const int start = NBINS - 1 - t * ch;

    int   c_t = 0;
    float s_t = 0.0f;
    #pragma unroll
    for (int j = 0; j < ch; ++j) { c_t += cnt[start - j]; s_t += sum[start - j]; }
    cs[t] = c_t;
    ss[t] = s_t;
    __syncthreads();

    // Hillis-Steele inclusive scan (top -> bottom order)
    for (int off = 1; off < SEL_THREADS; off <<= 1) {
        int cv = 0; float sv = 0.0f;
        if (t >= off) { cv = cs[t - off]; sv = ss[t - off]; }
        __syncthreads();
        cs[t] += cv;
        ss[t] += sv;
        __syncthreads();
    }

    const int   c_incl   = cs[t];
    const int   c_before = c_incl - c_t;
    const float s_before = ss[t] - s_t;

    if (c_before < k && k <= c_incl) {
        int   cum = c_before;
        float s   = s_before;
        float result = 0.0f;
        for (int j = 0; j < ch; ++j) {
            int b = start - j;
            int c = cnt[b];
            if (c == 0) continue;
            if (cum + c >= k) {
                int need = k - cum;
                float avg = sum[b] / (float)c;   // bin mean, tighter than center
                result = (s + (float)need * avg) / (float)k;
                break;
            }
            cum += c;
            s   += sum[b];
        }
        out[0] = result;
    }
}

extern "C" void kernel_launch(void* const* d_in, const int* in_sizes, int n_in,
                              void* d_out, int out_size, void* d_ws, size_t ws_size,
                              hipStream_t stream)
{
    const float* input  = (const float*)d_in[0];
    const float* target = (const float*)d_in[1];
    float* out = (float*)d_out;

    const int total  = in_sizes[0];
    const int n_rows = total / D_FEAT;            // 65536
    int k = (int)(0.3 * (double)n_rows);          // matches int(K_FRAC * n)
    if (k < 1) k = 1;
    if (k > n_rows) k = n_rows;

    // Workspace layout: rowmse[n_rows] | g_cnt[NBINS] | g_sum[NBINS]
    float* rowmse = (float*)d_ws;
    int*   g_cnt  = (int*)((char*)d_ws + (size_t)n_rows * sizeof(float));
    float* g_sum  = (float*)((char*)d_ws + (size_t)n_rows * sizeof(float)
                                         + (size_t)NBINS * sizeof(int));

    mse_rows_kernel<<<MAIN_BLOCKS, MAIN_THREADS, 0, stream>>>(
        input, target, n_rows, rowmse, g_cnt, g_sum);

    hist_kernel<<<HB_BLOCKS, HB_THREADS, 0, stream>>>(rowmse, n_rows, g_cnt, g_sum);

    scan_select_kernel<<<1, SEL_THREADS, 0, stream>>>(g_cnt, g_sum, k, out);
}